// Round 2
// baseline (1531.472 us; speedup 1.0000x reference)
//
#include <hip/hip_runtime.h>
#include <cstdint>

#define DIVUP(a,b) (((a)+(b)-1)/(b))

typedef __attribute__((ext_vector_type(4))) float f32x4;
typedef __attribute__((ext_vector_type(8))) _Float16 half8;

// Direct global->LDS DMA, 16B per lane. LDS dest is WAVE-UNIFORM base + lane*16.
__device__ __forceinline__ void gload_lds16(const void* g, void* l) {
  __builtin_amdgcn_global_load_lds(
      (const __attribute__((address_space(1))) void*)g,
      (__attribute__((address_space(3))) void*)l, 16, 0, 0);
}

__device__ __forceinline__ float cubicw(float x) {
  // PyTorch bicubic kernel, a = -0.75
  float ax = fabsf(x);
  float ax2 = ax * ax;
  float ax3 = ax2 * ax;
  if (ax <= 1.0f) return 1.25f * ax3 - 2.25f * ax2 + 1.0f;
  if (ax < 2.0f)  return -0.75f * ax3 + 3.75f * ax2 - 6.0f * ax + 3.0f;
  return 0.0f;
}

// S[b,pix] = sum_c x[b,c,pix]^2
__global__ void sumsq_kernel(const float* __restrict__ x, float* __restrict__ S,
                             int C, int HW, int total) {
  int i = blockIdx.x * blockDim.x + threadIdx.x;
  if (i >= total) return;
  int pix = i % HW, b = i / HW;
  const float* p = x + (size_t)b * C * HW + pix;
  float s = 0.f;
  for (int c = 0; c < C; ++c) { float v = p[(size_t)c * HW]; s += v * v; }
  S[i] = s;
}

// invn[b,p] = 1 / max(sqrt(3x3 zero-padded window sum of S), 1e-12)
__global__ void invnorm_kernel(const float* __restrict__ S, float* __restrict__ invn,
                               int H, int W, int total) {
  int i = blockIdx.x * blockDim.x + threadIdx.x;
  if (i >= total) return;
  int p = i % (H * W), b = i / (H * W);
  int ph = p / W, pw = p % W;
  const float* Sb = S + (size_t)b * H * W;
  float s = 0.f;
  for (int ki = 0; ki < 3; ++ki) {
    int y = ph + ki - 1;
    if (y < 0 || y >= H) continue;
    for (int kj = 0; kj < 3; ++kj) {
      int xx = pw + kj - 1;
      if (xx < 0 || xx >= W) continue;
      s += Sb[y * W + xx];
    }
  }
  float n = fmaxf(sqrtf(s), 1e-12f);
  invn[i] = 1.0f / n;
}

// l-layout descriptors (fp32, D-major) for levels 1/2
__global__ void desc_l_kernel(const float* __restrict__ x, const float* __restrict__ invn,
                              float* __restrict__ out, int C, int H, int W, int total) {
  int i = blockIdx.x * blockDim.x + threadIdx.x;
  if (i >= total) return;
  int HW = H * W, D = C * 9;
  int p = i % HW;
  int d = (i / HW) % D;
  int b = i / (HW * D);
  int c = d / 9, r = d % 9, ki = r / 3, kj = r % 3;
  int ph = p / W, pw = p % W;
  int y = ph + ki - 1, xx = pw + kj - 1;
  float v = 0.f;
  if (y >= 0 && y < H && xx >= 0 && xx < W) v = x[((size_t)(b * C + c) * H + y) * W + xx];
  out[i] = v * invn[b * HW + p];
}

// r-layout descriptors (fp32, N-major) for levels 1/2
__global__ void desc_r_kernel(const float* __restrict__ x, const float* __restrict__ invn,
                              float* __restrict__ out, int C, int H, int W, int total) {
  int i = blockIdx.x * blockDim.x + threadIdx.x;
  if (i >= total) return;
  int HW = H * W, D = C * 9;
  int d = i % D;
  int p = (i / D) % HW;
  int b = i / (D * HW);
  int c = d / 9, r = d % 9, ki = r / 3, kj = r % 3;
  int ph = p / W, pw = p % W;
  int y = ph + ki - 1, xx = pw + kj - 1;
  float v = 0.f;
  if (y >= 0 && y < H && xx >= 0 && xx < W) v = x[((size_t)(b * C + c) * H + y) * W + xx];
  out[i] = v * invn[b * HW + p];
}

// Level-3 split-f16 descriptors, pixel-major [B][4096][576]:
// hi = f16(v), lo = f16((v-hi)*4096)  (scaled to stay f16-normal)
__global__ void desc_split_kernel(const float* __restrict__ x, const float* __restrict__ invn,
                                  _Float16* __restrict__ hi, _Float16* __restrict__ lo,
                                  int C, int H, int W, int total) {
  int i = blockIdx.x * blockDim.x + threadIdx.x;
  if (i >= total) return;
  int c = i % C;
  int p = (i / C) % (H * W);
  int b = i / (C * H * W);
  int ph = p / W, pw = p % W;
  float s = invn[b * H * W + p];
  size_t obase = ((size_t)b * H * W + p) * (size_t)(C * 9) + (size_t)c * 9;
  const float* xb = x + (size_t)(b * C + c) * H * W;
#pragma unroll
  for (int r = 0; r < 9; ++r) {
    int y = ph + r / 3 - 1, xx = pw + r % 3 - 1;
    float v = 0.f;
    if (y >= 0 && y < H && xx >= 0 && xx < W) v = xb[y * W + xx] * s;
    _Float16 h = (_Float16)v;
    float hf = (float)h;
    _Float16 l = (_Float16)((v - hf) * 4096.0f);
    hi[obase + r] = h;
    lo[obase + r] = l;
  }
}

// Axis-2 (m / column) bicubic upsample: out[b][n][mo], mo in [0, Mout)
// (bicubic is separable; doing the m-pass first commutes exactly with the
//  n-pass done in the mfma epilogue, clamps included)
__global__ void upsample_m_kernel(const float* __restrict__ Rin, float* __restrict__ out,
                                  int Nrows, int Min, float invscale, int Mout, int total) {
  int i = blockIdx.x * blockDim.x + threadIdx.x;
  if (i >= total) return;
  int mo = i % Mout;
  int n = (i / Mout) % Nrows;
  int b = i / (Mout * Nrows);
  float src = (mo + 0.5f) * invscale - 0.5f;
  float f = floorf(src);
  float tt = src - f;
  int fi = (int)f;
  const float* Rb = Rin + ((size_t)b * Nrows + n) * Min;
  float s = 0.f;
#pragma unroll
  for (int tp = 0; tp < 4; ++tp) {
    int ii = min(max(fi + tp - 1, 0), Min - 1);
    s += cubicw(tt - (float)(tp - 1)) * Rb[ii];
  }
  out[i] = s;
}

__global__ void init_packed_kernel(unsigned long long* __restrict__ p, int n) {
  int i = blockIdx.x * blockDim.x + threadIdx.x;
  if (i < n) p[i] = 0ull;
}

// 64x64-tile fp32 GEMM (4x4 microtile), register-prefetch pipelined. R2.
__global__ __launch_bounds__(256)
void gemm64_kernel(const float* __restrict__ A, const float* __restrict__ B,
                   float* __restrict__ C, int M, int N, int K) {
  int b = blockIdx.z;
  const float* Ab = A + (size_t)b * M * K;
  const float* Bb = B + (size_t)b * K * N;
  __shared__ float As[16][68];
  __shared__ float Bs[16][64];
  int row0 = blockIdx.y * 64;
  int col0 = blockIdx.x * 64;
  int t = threadIdx.x;
  int tx = t & 15, ty = t >> 4;
  float acc[4][4] = {};
  int la_r = t >> 2;
  int la_k = (t & 3) << 2;
  int lb_r = t >> 4;
  int lb_c = (t & 15) << 2;
  const float* Aptr = Ab + (size_t)(row0 + la_r) * K + la_k;
  const float* Bptr = Bb + (size_t)lb_r * N + col0 + lb_c;
  float4 av = *(const float4*)(Aptr);
  float4 bv = *(const float4*)(Bptr);
  for (int k0 = 0; k0 < K; k0 += 16) {
    __syncthreads();
    As[la_k + 0][la_r] = av.x;
    As[la_k + 1][la_r] = av.y;
    As[la_k + 2][la_r] = av.z;
    As[la_k + 3][la_r] = av.w;
    *(float4*)&Bs[lb_r][lb_c] = bv;
    __syncthreads();
    if (k0 + 16 < K) {
      av = *(const float4*)(Aptr + k0 + 16);
      bv = *(const float4*)(Bptr + (size_t)(k0 + 16) * N);
    }
#pragma unroll
    for (int k = 0; k < 16; ++k) {
      float4 a = *(const float4*)&As[k][ty << 2];
      float4 bq = *(const float4*)&Bs[k][tx << 2];
      float av4[4] = {a.x, a.y, a.z, a.w};
      float bv4[4] = {bq.x, bq.y, bq.z, bq.w};
#pragma unroll
      for (int ii = 0; ii < 4; ++ii)
#pragma unroll
        for (int jj = 0; jj < 4; ++jj)
          acc[ii][jj] = fmaf(av4[ii], bv4[jj], acc[ii][jj]);
    }
  }
  float* Cb = C + (size_t)b * M * N;
#pragma unroll
  for (int ii = 0; ii < 4; ++ii) {
    float4 v = make_float4(acc[ii][0], acc[ii][1], acc[ii][2], acc[ii][3]);
    *(float4*)&Cb[(size_t)(row0 + (ty << 2) + ii) * N + col0 + (tx << 2)] = v;
  }
}

// Split-K variant with atomicAdd epilogue (for the tiny R1 GEMM: 32 blocks
// would leave 87% of the CUs idle; SK=8 -> 256 blocks). C must be zeroed.
__global__ __launch_bounds__(256)
void gemm64sk_kernel(const float* __restrict__ A, const float* __restrict__ B,
                     float* __restrict__ C, int M, int N, int K, int SK) {
  int zz = blockIdx.z;
  int b = zz / SK, kc = zz % SK;
  int kchunk = K / SK;                    // must be a multiple of 16
  int kbeg = kc * kchunk, kend = kbeg + kchunk;
  const float* Ab = A + (size_t)b * M * K;
  const float* Bb = B + (size_t)b * K * N;
  __shared__ float As[16][68];
  __shared__ float Bs[16][64];
  int row0 = blockIdx.y * 64;
  int col0 = blockIdx.x * 64;
  int t = threadIdx.x;
  int tx = t & 15, ty = t >> 4;
  float acc[4][4] = {};
  int la_r = t >> 2;
  int la_k = (t & 3) << 2;
  int lb_r = t >> 4;
  int lb_c = (t & 15) << 2;
  const float* Aptr = Ab + (size_t)(row0 + la_r) * K + la_k;
  const float* Bptr = Bb + (size_t)lb_r * N + col0 + lb_c;
  float4 av = *(const float4*)(Aptr + kbeg);
  float4 bv = *(const float4*)(Bptr + (size_t)kbeg * N);
  for (int k0 = kbeg; k0 < kend; k0 += 16) {
    __syncthreads();
    As[la_k + 0][la_r] = av.x;
    As[la_k + 1][la_r] = av.y;
    As[la_k + 2][la_r] = av.z;
    As[la_k + 3][la_r] = av.w;
    *(float4*)&Bs[lb_r][lb_c] = bv;
    __syncthreads();
    if (k0 + 16 < kend) {
      av = *(const float4*)(Aptr + k0 + 16);
      bv = *(const float4*)(Bptr + (size_t)(k0 + 16) * N);
    }
#pragma unroll
    for (int k = 0; k < 16; ++k) {
      float4 a = *(const float4*)&As[k][ty << 2];
      float4 bq = *(const float4*)&Bs[k][tx << 2];
      float av4[4] = {a.x, a.y, a.z, a.w};
      float bv4[4] = {bq.x, bq.y, bq.z, bq.w};
#pragma unroll
      for (int ii = 0; ii < 4; ++ii)
#pragma unroll
        for (int jj = 0; jj < 4; ++jj)
          acc[ii][jj] = fmaf(av4[ii], bv4[jj], acc[ii][jj]);
    }
  }
  float* Cb = C + (size_t)b * M * N;
#pragma unroll
  for (int ii = 0; ii < 4; ++ii)
#pragma unroll
    for (int jj = 0; jj < 4; ++jj)
      atomicAdd(&Cb[(size_t)(row0 + (ty << 2) + ii) * N + col0 + (tx << 2) + jj],
                acc[ii][jj]);
}

// MFMA split-f16 GEMM, 128x128 workgroup tile, wave=64x64 (4x4 of 16x16x32),
// fused bicubic-tap add + /3 + packed max/argmax over the ref axis (rows).
// This round:
//  - prefetch DMA issued immediately after the barrier -> overlaps the FULL
//    iteration (ds_read + MFMA), not just the MFMA phase.
//  - epilogue taps now run along the PRE-UPSAMPLED m axis (up2m/up1m):
//    per-block 36x128 + 12x128 f32 slices staged into the (now free) LDS,
//    taps become <=2-way-conflict LDS reads instead of ~1GB of scattered
//    4B L2 loads.
__global__ __launch_bounds__(256, 2)
void mfma_fused_kernel(const _Float16* __restrict__ Ahi, const _Float16* __restrict__ Alo,
                       const _Float16* __restrict__ Bhi, const _Float16* __restrict__ Blo,
                       const float* __restrict__ up2m, const float* __restrict__ up1m,
                       unsigned long long* __restrict__ packed) {
  const int K = 576;
  // ---- XCD swizzle: grid is (32,32,2) = 2048 blocks; 2048 % 8 == 0 -> bijective
  int bid = (blockIdx.z * 32 + blockIdx.y) * 32 + blockIdx.x;
  int swz = (bid & 7) * 256 + (bid >> 3);
  int bx = swz & 31;
  int by = (swz >> 5) & 31;
  int b  = swz >> 10;

  int row0 = by * 128;   // ref axis (n) — argmax axis
  int col0 = bx * 128;   // lr axis (m) — output positions
  int t = threadIdx.x;
  int lane = t & 63, wave = t >> 6;
  int wy = wave & 1, wx = wave >> 1;
  int quad = lane >> 4, lm = lane & 15;

  // LDS: [buf:2][plane:4][8KB tile]. plane 0=AH 1=AL 2=BH 3=BL.
  __shared__ _Float16 lds[2 * 4 * 4096];

  // ---- staging source offsets (per-lane, bytes into a [128][K] half-plane).
  // Linear dest chunk d = wave*128 + h*64 + lane; invert the chunk swizzle
  // (chunk3 ^= line&7) to find which (row, col16) to fetch into that slot.
  int off[2];
#pragma unroll
  for (int h = 0; h < 2; ++h) {
    int d = wave * 128 + h * 64 + lane;
    int line = d >> 3;
    int c3 = (d & 7) ^ (line & 7);
    int row = (line << 1) | (c3 >> 2);
    int c = c3 & 3;
    off[h] = row * (K * 2) + c * 16;
  }
  const char* pg[4];
  pg[0] = (const char*)Ahi + ((size_t)b * 4096 + row0) * (size_t)K * 2;
  pg[1] = (const char*)Alo + ((size_t)b * 4096 + row0) * (size_t)K * 2;
  pg[2] = (const char*)Bhi + ((size_t)b * 4096 + col0) * (size_t)K * 2;
  pg[3] = (const char*)Blo + ((size_t)b * 4096 + col0) * (size_t)K * 2;

  // ---- fragment ds_read addresses (bytes into an 8KB plane), swizzled.
  int ra[4], rb[4];
#pragma unroll
  for (int i = 0; i < 4; ++i) {
    int rowa = wy * 64 + i * 16 + lm;
    int la_ = rowa >> 1;
    ra[i] = la_ * 128 + (((((rowa & 1) << 2) | quad) ^ (la_ & 7)) << 4);
    int rowb = wx * 64 + i * 16 + lm;
    int lb_ = rowb >> 1;
    rb[i] = lb_ * 128 + (((((rowb & 1) << 2) | quad) ^ (lb_ & 7)) << 4);
  }

  f32x4 S1[4][4] = {};
  f32x4 S2[4][4] = {};

  // stage tile 0 into buf 0
#pragma unroll
  for (int p = 0; p < 4; ++p) {
    char* lw = (char*)lds + p * 8192 + wave * 2048;
    gload_lds16(pg[p] + off[0], lw);
    gload_lds16(pg[p] + off[1], lw + 1024);
  }

  int buf = 0;
  for (int t18 = 0; t18 < 18; ++t18) {
    __syncthreads();   // compiler vmcnt(0) drains the DMA targeting buf
    // issue next tile's DMA NOW -> it has the whole iteration to land
    if (t18 + 1 < 18) {
      int kbyte = (t18 + 1) * 64;
#pragma unroll
      for (int p = 0; p < 4; ++p) {
        char* lw = (char*)lds + (buf ^ 1) * 32768 + p * 8192 + wave * 2048;
        gload_lds16(pg[p] + kbyte + off[0], lw);
        gload_lds16(pg[p] + kbyte + off[1], lw + 1024);
      }
    }
    const char* lb = (const char*)lds + buf * 32768;
    half8 aH[4], aL[4], bH[4], bL[4];
#pragma unroll
    for (int i = 0; i < 4; ++i) {
      aH[i] = *(const half8*)(lb + ra[i]);
      aL[i] = *(const half8*)(lb + 8192 + ra[i]);
      bH[i] = *(const half8*)(lb + 16384 + rb[i]);
      bL[i] = *(const half8*)(lb + 24576 + rb[i]);
    }
#pragma unroll
    for (int i = 0; i < 4; ++i)
#pragma unroll
      for (int j = 0; j < 4; ++j) {
        S1[i][j] = __builtin_amdgcn_mfma_f32_16x16x32_f16(aH[i], bH[j], S1[i][j], 0, 0, 0);
        S2[i][j] = __builtin_amdgcn_mfma_f32_16x16x32_f16(aH[i], bL[j], S2[i][j], 0, 0, 0);
        S2[i][j] = __builtin_amdgcn_mfma_f32_16x16x32_f16(aL[i], bH[j], S2[i][j], 0, 0, 0);
      }
    buf ^= 1;
  }

  // ---- epilogue: stage n-tap slices of up2m/up1m into LDS, then
  //      v = S1 + S2*2^-12 + n-bicubic(up2m) + n-bicubic(up1m); /3; max/argmax.
  __syncthreads();                           // main loop done; reuse LDS
  float* up2s = (float*)lds;                 // [36][132]
  float* up1s = (float*)lds + 36 * 132;      // [12][132]
  int base2 = (row0 >> 2) - 2;               // up2m row window [base2, base2+35]
  int base1 = (row0 >> 4) - 2;               // up1m row window [base1, base1+11]
  {
    const float* u2 = up2m + (size_t)b * 1024 * 4096;
    const float* u1 = up1m + (size_t)b * 256 * 4096;
    for (int idx = t; idx < 36 * 128; idx += 256) {
      int rr = idx >> 7, cc = idx & 127;
      int gr = min(max(base2 + rr, 0), 1023);
      up2s[rr * 132 + cc] = u2[(size_t)gr * 4096 + col0 + cc];
    }
    for (int idx = t; idx < 12 * 128; idx += 256) {
      int rr = idx >> 7, cc = idx & 127;
      int gr = min(max(base1 + rr, 0), 255);
      up1s[rr * 132 + cc] = u1[(size_t)gr * 4096 + col0 + cc];
    }
  }
  __syncthreads();

  const float inv4096 = 1.0f / 4096.0f;
  unsigned long long best[4] = {0ull, 0ull, 0ull, 0ull};
#pragma unroll
  for (int i = 0; i < 4; ++i) {
#pragma unroll
    for (int r = 0; r < 4; ++r) {
      int gn = row0 + wy * 64 + i * 16 + quad * 4 + r;
      float s2 = (gn + 0.5f) * 0.25f - 0.5f;
      float f2 = floorf(s2); float t2 = s2 - f2; int i2 = (int)f2;
      int sl2 = i2 - 1 - base2;              // 0..32
      float w2[4];
      float s1 = (gn + 0.5f) * 0.0625f - 0.5f;
      float f1 = floorf(s1); float t1 = s1 - f1; int i1 = (int)f1;
      int sl1 = i1 - 1 - base1;              // 0..8
      float w1[4];
#pragma unroll
      for (int tp = 0; tp < 4; ++tp) {
        w2[tp] = cubicw(t2 - (float)(tp - 1));
        w1[tp] = cubicw(t1 - (float)(tp - 1));
      }
      const float* p2 = up2s + sl2 * 132;
      const float* p1 = up1s + sl1 * 132;
#pragma unroll
      for (int j = 0; j < 4; ++j) {
        int gml = wx * 64 + j * 16 + lm;
        float u = w2[0] * p2[gml]       + w2[1] * p2[132 + gml]
                + w2[2] * p2[264 + gml] + w2[3] * p2[396 + gml]
                + w1[0] * p1[gml]       + w1[1] * p1[132 + gml]
                + w1[2] * p1[264 + gml] + w1[3] * p1[396 + gml];
        float v = (S1[i][j][r] + S2[i][j][r] * inv4096 + u) * (1.0f / 3.0f);
        unsigned int fb = __float_as_uint(v);
        unsigned int key = (fb & 0x80000000u) ? ~fb : (fb | 0x80000000u);
        unsigned long long pk = ((unsigned long long)key << 32)
                              | (unsigned long long)(0xFFFFFFFFu - (unsigned)gn);
        best[j] = best[j] > pk ? best[j] : pk;
      }
    }
  }
#pragma unroll
  for (int j = 0; j < 4; ++j) {
    unsigned long long bb = best[j];
    unsigned long long o;
    o = __shfl_xor(bb, 16); bb = bb > o ? bb : o;
    o = __shfl_xor(bb, 32); bb = bb > o ? bb : o;
    if (lane < 16) {
      int gm = col0 + wx * 64 + j * 16 + lm;
      atomicMax(&packed[(size_t)b * 4096 + gm], bb);
    }
  }
}

__global__ void finalize_kernel(const unsigned long long* __restrict__ packed,
                                float* __restrict__ s3_out, int* __restrict__ arg, int total) {
  int i = blockIdx.x * blockDim.x + threadIdx.x;
  if (i >= total) return;
  unsigned long long pk = packed[i];
  unsigned int key = (unsigned int)(pk >> 32);
  unsigned int fb = (key & 0x80000000u) ? (key ^ 0x80000000u) : ~key;
  s3_out[i] = __uint_as_float(fb);
  arg[i] = (int)(0xFFFFFFFFu - (unsigned int)(pk & 0xFFFFFFFFull));
}

// Batched 2D transpose: out[b][s][r] = in[b][r][s].  R, S multiples of 32.
__global__ __launch_bounds__(256)
void transpose_kernel(const float* __restrict__ in, float* __restrict__ out,
                      int R, int S) {
  __shared__ float tile[32][33];
  int b = blockIdx.z;
  int s0 = blockIdx.x * 32, r0 = blockIdx.y * 32;
  int tx = threadIdx.x & 31, ty = threadIdx.x >> 5;   // ty in 0..7
  const float* ib = in + (size_t)b * R * S;
  float* ob = out + (size_t)b * R * S;
#pragma unroll
  for (int k = 0; k < 4; ++k)
    tile[ty + 8 * k][tx] = ib[(size_t)(r0 + ty + 8 * k) * S + s0 + tx];
  __syncthreads();
#pragma unroll
  for (int k = 0; k < 4; ++k)
    ob[(size_t)(s0 + ty + 8 * k) * R + r0 + tx] = tile[tx][ty + 8 * k];
}

// Channel-last fold-gather: lanes map to c (fastest dim) so every tap is a
// contiguous C*4B read from refT [b][h][w][c]; writes TT [b][h][w][c].
template<int KK, int SS, int PP, int CL2, int WL2>
__global__ void fold_gather_cl_kernel(const float* __restrict__ refT,
                                      const int* __restrict__ arg,
                                      float* __restrict__ TT, int total) {
  const int C = 1 << CL2, W = 1 << WL2;
  int i = blockIdx.x * blockDim.x + threadIdx.x;
  if (i >= total) return;
  int c = i & (C - 1);
  int p = i >> CL2;                 // p = (b*H + h)*W + w   (H == W)
  int w = p & (W - 1);
  int h = (p >> WL2) & (W - 1);
  int b = p >> (2 * WL2);
  int y = h + PP, x = w + PP;
  int ho_lo = (y - KK + 1) > 0 ? (y - KK + 1 + SS - 1) / SS : 0;
  int ho_hi = min(63, y / SS);
  int wo_lo = (x - KK + 1) > 0 ? (x - KK + 1 + SS - 1) / SS : 0;
  int wo_hi = min(63, x / SS);
  const int* argb = arg + b * 4096;
  const float* refb = refT + ((size_t)b << (2 * WL2 + CL2));
  float acc = 0.f;
  for (int ho = ho_lo; ho <= ho_hi; ++ho) {
    int ki = y - SS * ho;
    for (int wo = wo_lo; wo <= wo_hi; ++wo) {
      int kj = x - SS * wo;
      int q = argb[(ho << 6) + wo];
      int qh = q >> 6, qw = q & 63;
      int ry = SS * qh + ki - PP;
      int rx = SS * qw + kj - PP;
      if (ry >= 0 && ry < W && rx >= 0 && rx < W)
        acc += refb[(((size_t)ry << WL2) + rx << CL2) + c];
    }
  }
  TT[(size_t)p * C + c] = acc * (1.0f / 9.0f);
}

extern "C" void kernel_launch(void* const* d_in, const int* in_sizes, int n_in,
                              void* d_out, int out_size, void* d_ws, size_t ws_size,
                              hipStream_t stream) {
  const float* lrsr1 = (const float*)d_in[0];
  const float* lrsr2 = (const float*)d_in[1];
  const float* lrsr3 = (const float*)d_in[2];
  const float* refsr1 = (const float*)d_in[3];
  const float* refsr2 = (const float*)d_in[4];
  const float* refsr3 = (const float*)d_in[5];
  const float* ref1 = (const float*)d_in[6];
  const float* ref2 = (const float*)d_in[7];
  const float* ref3 = (const float*)d_in[8];
  float* out = (float*)d_out;
  float* ws = (float*)d_ws;

  const int B = 2;
  // level-3 f16 planes occupy the first region: 4 planes x [2][4096][576] halves
  size_t off_planes = 0;
  size_t off_r2n = off_planes + (size_t)B * 4096 * 576 * 2; // floats (= 4 half-planes)
  size_t off_l2n = off_r2n + (size_t)B * 1024 * 1152;   // [2,1152,1024]
  size_t off_r1n = off_l2n + (size_t)B * 1152 * 1024;   // [2,256,2304]
  size_t off_l1n = off_r1n + (size_t)B * 256 * 2304;    // [2,2304,256]
  size_t off_R2  = off_l1n + (size_t)B * 2304 * 256;    // [2,1024,1024]
  size_t off_R1  = off_R2  + (size_t)B * 1024 * 1024;   // [2,256,256]
  size_t off_up2 = off_R1  + (size_t)B * 256 * 256;     // [2,1024,4096] (m-upsampled)
  size_t off_up1 = off_up2 + (size_t)B * 1024 * 4096;   // [2,256,4096]
  size_t off_S   = off_up1 + (size_t)B * 256 * 4096;    // [2,4096]
  size_t off_invn= off_S   + (size_t)B * 4096;          // [2,4096]
  size_t off_pk  = off_invn+ (size_t)B * 4096;          // [2,4096] u64
  size_t off_arg = off_pk  + (size_t)B * 4096 * 2;      // [2,4096] int

  const size_t PLANE = (size_t)B * 4096 * 576;          // halves per plane
  _Float16* r3hi = (_Float16*)(ws + off_planes);
  _Float16* r3lo = r3hi + PLANE;
  _Float16* l3hi = r3lo + PLANE;
  _Float16* l3lo = l3hi + PLANE;

  auto run_desc32 = [&](const float* x, int C, int H, int W, float* outbuf, bool r_layout) {
    int HW = H * W;
    int tS = B * HW;
    sumsq_kernel<<<DIVUP(tS, 256), 256, 0, stream>>>(x, ws + off_S, C, HW, tS);
    invnorm_kernel<<<DIVUP(tS, 256), 256, 0, stream>>>(ws + off_S, ws + off_invn, H, W, tS);
    int tD = B * C * 9 * HW;
    if (r_layout)
      desc_r_kernel<<<DIVUP(tD, 256), 256, 0, stream>>>(x, ws + off_invn, outbuf, C, H, W, tD);
    else
      desc_l_kernel<<<DIVUP(tD, 256), 256, 0, stream>>>(x, ws + off_invn, outbuf, C, H, W, tD);
  };
  auto run_desc_split = [&](const float* x, _Float16* hi, _Float16* lo) {
    int C = 64, H = 64, W = 64, HW = H * W;
    int tS = B * HW;
    sumsq_kernel<<<DIVUP(tS, 256), 256, 0, stream>>>(x, ws + off_S, C, HW, tS);
    invnorm_kernel<<<DIVUP(tS, 256), 256, 0, stream>>>(ws + off_S, ws + off_invn, H, W, tS);
    int tD = B * C * HW;
    desc_split_kernel<<<DIVUP(tD, 256), 256, 0, stream>>>(x, ws + off_invn, hi, lo, C, H, W, tD);
  };

  // level 3 split-f16 descriptors (both pixel-major [4096][576])
  run_desc_split(refsr3, r3hi, r3lo);
  run_desc_split(lrsr3, l3hi, l3lo);
  // levels 1/2 fp32 descriptors
  run_desc32(lrsr2, 128, 32, 32, ws + off_l2n, false);
  run_desc32(refsr2, 128, 32, 32, ws + off_r2n, true);
  run_desc32(lrsr1, 256, 16, 16, ws + off_l1n, false);
  run_desc32(refsr1, 256, 16, 16, ws + off_r1n, true);

  // small correlation GEMMs R2 (plain), R1 (split-K x8, 256 blocks)
  {
    dim3 g(1024 / 64, 1024 / 64, B);
    gemm64_kernel<<<g, 256, 0, stream>>>(ws + off_r2n, ws + off_l2n, ws + off_R2,
                                         1024, 1024, 1152);
  }
  {
    init_packed_kernel<<<DIVUP(65536, 256), 256, 0, stream>>>(
        (unsigned long long*)(ws + off_R1), 65536);   // zero R1 (2*256*256 f32)
    dim3 g(256 / 64, 256 / 64, B * 8);
    gemm64sk_kernel<<<g, 256, 0, stream>>>(ws + off_r1n, ws + off_l1n, ws + off_R1,
                                           256, 256, 2304, 8);
  }

  // axis-2 (m) bicubic upsample of R2 (x4) and R1 (x16) to 4096 cols
  {
    int tU2 = B * 1024 * 4096;
    upsample_m_kernel<<<DIVUP(tU2, 256), 256, 0, stream>>>(ws + off_R2, ws + off_up2,
                                                           1024, 1024, 0.25f, 4096, tU2);
    int tU1 = B * 256 * 4096;
    upsample_m_kernel<<<DIVUP(tU1, 256), 256, 0, stream>>>(ws + off_R1, ws + off_up1,
                                                           256, 256, 0.0625f, 4096, tU1);
  }

  unsigned long long* pk = (unsigned long long*)(ws + off_pk);
  init_packed_kernel<<<DIVUP(B * 4096, 256), 256, 0, stream>>>(pk, B * 4096);

  // fused R3 MFMA GEMM + bicubic add + max/argmax
  {
    dim3 g(4096 / 128, 4096 / 128, B);
    mfma_fused_kernel<<<g, 256, 0, stream>>>(r3hi, r3lo, l3hi, l3lo,
                                             ws + off_up2, ws + off_up1, pk);
  }

  int* argp = (int*)(ws + off_arg);
  finalize_kernel<<<DIVUP(B * 4096, 256), 256, 0, stream>>>(pk, out, argp, B * 4096);

  // transfer: fold(gather(unfold(ref_lvX)))/9 — channel-last pipeline.
  // Dead regions reused: refT at ws+0 (planes region, 9.44M floats),
  // TT at ws+off_up2 (8.39M floats).
  float* refT = ws + off_planes;
  float* TT = ws + off_up2;
  float* T3 = out + 8192;
  float* T2 = T3 + (size_t)B * 256 * 64 * 64;
  float* T1 = T2 + (size_t)B * 128 * 128 * 128;
  // ---- T3: C=256, P=4096 (64x64)
  {
    dim3 g1(4096 / 32, 256 / 32, B);
    transpose_kernel<<<g1, 256, 0, stream>>>(ref3, refT, 256, 4096);
    int tt = B * 4096 * 256;
    fold_gather_cl_kernel<3, 1, 1, 8, 6><<<DIVUP(tt, 256), 256, 0, stream>>>(refT, argp, TT, tt);
    dim3 g2(256 / 32, 4096 / 32, B);
    transpose_kernel<<<g2, 256, 0, stream>>>(TT, T3, 4096, 256);
  }
  // ---- T2: C=128, P=16384 (128x128)
  {
    dim3 g1(16384 / 32, 128 / 32, B);
    transpose_kernel<<<g1, 256, 0, stream>>>(ref2, refT, 128, 16384);
    int tt = B * 16384 * 128;
    fold_gather_cl_kernel<6, 2, 2, 7, 7><<<DIVUP(tt, 256), 256, 0, stream>>>(refT, argp, TT, tt);
    dim3 g2(128 / 32, 16384 / 32, B);
    transpose_kernel<<<g2, 256, 0, stream>>>(TT, T2, 16384, 128);
  }
  // ---- T1: C=64, P=65536 (256x256)
  {
    dim3 g1(65536 / 32, 64 / 32, B);
    transpose_kernel<<<g1, 256, 0, stream>>>(ref1, refT, 64, 65536);
    int tt = B * 65536 * 64;
    fold_gather_cl_kernel<12, 4, 4, 6, 8><<<DIVUP(tt, 256), 256, 0, stream>>>(refT, argp, TT, tt);
    dim3 g2(64 / 32, 65536 / 32, B);
    transpose_kernel<<<g2, 256, 0, stream>>>(TT, T1, 65536, 64);
  }
}